// Round 1
// 165.685 us; speedup vs baseline: 1.1945x; 1.1945x over previous
//
#include <hip/hip_runtime.h>
#include <hip/hip_bf16.h>
#include <math.h>

#define LSEQ 32768
#define DMODEL 256
#define DHID 256
#define NCH 512                 // interleaved [re,im] hidden channels: col 2h=re, 2h+1=im
#define CHUNK 128
#define NCHUNKS (LSEQ / CHUNK)  // 256

typedef __bf16 bf16_t;
typedef _Float16 f16_t;
typedef __bf16 bf16x8 __attribute__((ext_vector_type(8)));
typedef __bf16 bf16x4 __attribute__((ext_vector_type(4)));
typedef float f32x4 __attribute__((ext_vector_type(4)));

__device__ __forceinline__ void async_load16(const void* g, void* l) {
  __builtin_amdgcn_global_load_lds((__attribute__((address_space(1))) void*)g,
                                   (__attribute__((address_space(3))) void*)l,
                                   16, 0, 0);
}

__device__ __forceinline__ float f16tof(unsigned int u) {
  return (float)__builtin_bit_cast(_Float16, (unsigned short)(u & 0xffffu));
}
__device__ __forceinline__ unsigned short fTobf(float f) {
  return __builtin_bit_cast(unsigned short, (bf16_t)f);
}

// ---------------- prep: lambda, lambda^32, lambda^CHUNK (fp64 phase) ---------
__global__ void prep_params(const float* __restrict__ nu_log,
                            const float* __restrict__ theta_log,
                            float* __restrict__ lam /* [6*DHID] */) {
  int h = threadIdx.x;
  if (h < DHID) {
    double nu = exp((double)nu_log[h]);
    double th = exp((double)theta_log[h]);
    double mag = exp(-nu);
    lam[h]            = (float)(mag * cos(th));
    lam[DHID + h]     = (float)(mag * sin(th));
    double magC = exp(-(double)CHUNK * nu);
    double phC  = fmod((double)CHUNK * th, 6.283185307179586);
    lam[2 * DHID + h] = (float)(magC * cos(phC));
    lam[3 * DHID + h] = (float)(magC * sin(phC));
    double mag32 = exp(-32.0 * nu);
    double ph32  = fmod(32.0 * th, 6.283185307179586);
    lam[4 * DHID + h] = (float)(mag32 * cos(ph32));
    lam[5 * DHID + h] = (float)(mag32 * sin(ph32));
  }
}

// W1[n][k], n interleaved: n=2h -> B_re[h][k]*gamma[h]; n=2h+1 -> B_im[h][k]*gamma[h]
__global__ void pack_w1(const float* __restrict__ B_re, const float* __restrict__ B_im,
                        const float* __restrict__ gamma_log, bf16_t* __restrict__ W1) {
  int n = blockIdx.x, k = threadIdx.x;
  int h = n >> 1;
  float g = expf(gamma_log[h]);
  float v = (((n & 1) == 0) ? B_re[h * DMODEL + k] : B_im[h * DMODEL + k]) * g;
  W1[n * DMODEL + k] = (bf16_t)v;
}

// W2[m][k], k interleaved: k=2h -> C_re[m][h]; k=2h+1 -> -C_im[m][h]
__global__ void pack_w2(const float* __restrict__ C_re, const float* __restrict__ C_im,
                        bf16_t* __restrict__ W2) {
  int m = blockIdx.x, k = threadIdx.x;  // 512 threads
  int h = k >> 1;
  float v = ((k & 1) == 0) ? C_re[m * DHID + h] : -C_im[m * DHID + h];
  W2[m * NCH + k] = (bf16_t)v;
}

__global__ void convert_x(const float* __restrict__ x, bf16_t* __restrict__ xb) {
  int i = blockIdx.x * 256 + threadIdx.x;
  float4 v = ((const float4*)x)[i];
  bf16x4 o = {(bf16_t)v.x, (bf16_t)v.y, (bf16_t)v.z, (bf16_t)v.w};
  ((bf16x4*)xb)[i] = o;
}

// ---------------- kernel A: GEMM1 (chunk tile) + fp16 Bu store + local E ----
// grid (2, NCHUNKS), 512 threads (8 waves, 2x4). Tile 128(t) x 256(ch), K=256.
// Bu global layout: [L][1024B] fp16, byte cb stored at cb ^ ((t&7)<<4).
__global__ __launch_bounds__(512) void gemm1_scan(
    const bf16_t* __restrict__ A, const bf16_t* __restrict__ Bw,
    f16_t* __restrict__ Bu, const float* __restrict__ lam,
    float* __restrict__ E) {
  __shared__ __align__(16) char smem[69632];  // 68 KB
  bf16_t* As = (bf16_t*)smem;                 // [128][32] bf16 = 8 KB
  bf16_t* Bs = (bf16_t*)(smem + 8192);        // [256][32] bf16 = 16 KB
  char*   Bt = smem;                          // [128][512B] fp16 swizzled (aliases As/Bs)
  float*  Ep = (float*)(smem + 65536);        // [4][128][2] f32 = 4 KB

  const int tid = threadIdx.x;
  const int gx = blockIdx.x;          // channel half: pairs [gx*128, gx*128+128)
  const int c  = blockIdx.y;          // chunk
  const int r0 = c * CHUNK;
  const int c0 = gx * 256;            // column offset into the 512-wide Bu
  const int wave = tid >> 6, lane = tid & 63;
  const int wm = wave & 1, wn = wave >> 1;
  const int lrow = lane & 15, lk = lane >> 4;
  const int ra = tid >> 2, ka = (tid & 3) * 8;

  f32x4 acc[4][4] = {};

  for (int k0 = 0; k0 < DMODEL; k0 += 32) {
    __syncthreads();
    async_load16(A + (size_t)(r0 + ra) * DMODEL + k0 + ka, (char*)As + tid * 16);
    async_load16(Bw + (size_t)(c0 + ra) * DMODEL + k0 + ka, (char*)Bs + tid * 16);
    async_load16(Bw + (size_t)(c0 + 128 + ra) * DMODEL + k0 + ka,
                 (char*)Bs + 8192 + tid * 16);
    __syncthreads();
    bf16x8 af[4], bfr[4];
#pragma unroll
    for (int i = 0; i < 4; ++i)
      af[i] = *(const bf16x8*)(As + (wm * 64 + i * 16 + lrow) * 32 + lk * 8);
#pragma unroll
    for (int j = 0; j < 4; ++j)
      bfr[j] = *(const bf16x8*)(Bs + (wn * 64 + j * 16 + lrow) * 32 + lk * 8);
#pragma unroll
    for (int i = 0; i < 4; ++i)
#pragma unroll
      for (int j = 0; j < 4; ++j)
        acc[i][j] = __builtin_amdgcn_mfma_f32_16x16x32_bf16(af[i], bfr[j], acc[i][j], 0, 0, 0);
  }
  __syncthreads();  // all frag reads done before overwriting As/Bs with Bt

  // acc -> Bt (fp16, swizzled local half-rows of 512B)
#pragma unroll
  for (int i = 0; i < 4; ++i)
#pragma unroll
    for (int r = 0; r < 4; ++r) {
      int row = wm * 64 + i * 16 + lk * 4 + r;
      int key = (row & 7) << 4;
#pragma unroll
      for (int j = 0; j < 4; ++j) {
        int col = wn * 64 + j * 16 + lrow;
        *(f16_t*)(Bt + row * 512 + ((col * 2) ^ key)) = (f16_t)acc[i][j][r];
      }
    }
  __syncthreads();

  // Bt -> global Bu (byte-identical image; (r0+row)&7 == row&7 since r0%128==0)
  char* dst = (char*)Bu + (size_t)r0 * 1024 + gx * 512;
#pragma unroll
  for (int it = 0; it < 8; ++it) {
    int idx = it * 512 + tid;
    int row = idx >> 5, off = (idx & 31) * 16;
    *(f32x4*)(dst + (size_t)row * 1024 + off) = *(const f32x4*)(Bt + row * 512 + off);
  }

  // local end-state: 4 time segments of 32 per channel pair, then Horner w/ lambda^32
  {
    int p = tid & 127, seg = tid >> 7;
    int h = gx * 128 + p;
    float lre = lam[h], lim = lam[DHID + h];
    float sre = 0.f, sim = 0.f;
    int cb = 4 * p;
#pragma unroll 4
    for (int t = 0; t < 32; ++t) {
      int row = seg * 32 + t;
      unsigned int w = *(const unsigned int*)(Bt + row * 512 + (cb ^ ((row & 7) << 4)));
      float bre = f16tof(w), bim = f16tof(w >> 16);
      float nre = fmaf(lre, sre, fmaf(-lim, sim, bre));
      float nim = fmaf(lre, sim, fmaf(lim, sre, bim));
      sre = nre; sim = nim;
    }
    Ep[seg * 256 + 2 * p]     = sre;
    Ep[seg * 256 + 2 * p + 1] = sim;
  }
  __syncthreads();
  if (tid < 128) {
    int p = tid, h = gx * 128 + p;
    float ar = lam[4 * DHID + h], ai = lam[5 * DHID + h];
    float er = Ep[2 * p], ei = Ep[2 * p + 1];
#pragma unroll
    for (int s = 1; s < 4; ++s) {
      float tr = fmaf(ar, er, fmaf(-ai, ei, Ep[s * 256 + 2 * p]));
      float ti = fmaf(ar, ei, fmaf(ai, er, Ep[s * 256 + 2 * p + 1]));
      er = tr; ei = ti;
    }
    E[c * NCH + h]       = er;
    E[c * NCH + 256 + h] = ei;
  }
}

// ---------------- pass 2: Kogge-Stone over chunks (unchanged) ----------------
__global__ void scan_pass2(const float* __restrict__ E, const float* __restrict__ lam,
                           float* __restrict__ Sc) {
  int h = blockIdx.x, c = threadIdx.x;
  __shared__ float Ar[NCHUNKS], Ai[NCHUNKS], br[NCHUNKS], bi[NCHUNKS];
  float aR = lam[2 * DHID + h], aI = lam[3 * DHID + h];
  float bR = E[c * NCH + h], bI = E[c * NCH + 256 + h];
  Ar[c] = aR; Ai[c] = aI; br[c] = bR; bi[c] = bI;
  __syncthreads();
  for (int off = 1; off < NCHUNKS; off <<= 1) {
    float paR = 0, paI = 0, pbR = 0, pbI = 0;
    bool has = (c >= off);
    if (has) { paR = Ar[c - off]; paI = Ai[c - off]; pbR = br[c - off]; pbI = bi[c - off]; }
    __syncthreads();
    if (has) {
      float nAR = aR * paR - aI * paI;
      float nAI = aR * paI + aI * paR;
      float nbR = aR * pbR - aI * pbI + bR;
      float nbI = aR * pbI + aI * pbR + bI;
      aR = nAR; aI = nAI; bR = nbR; bI = nbI;
      Ar[c] = aR; Ai[c] = aI; br[c] = bR; bi[c] = bI;
    }
    __syncthreads();
  }
  float inR = (c > 0) ? br[c - 1] : 0.f;
  float inI = (c > 0) ? bi[c - 1] : 0.f;
  Sc[c * NCH + h]       = inR;
  Sc[c * NCH + 256 + h] = inI;
}

// ---------------- kernel C: stage chunk -> in-place scan -> GEMM2 + D-fuse ---
// grid NCHUNKS, 512 threads. LDS: H 128KB + Bs 16KB = 144KB, 1 block/CU.
__global__ __launch_bounds__(512) void scan_gemm2(
    const f16_t* __restrict__ Bu, const bf16_t* __restrict__ W2,
    const float* __restrict__ lam, const float* __restrict__ Sc,
    const float* __restrict__ X, const float* __restrict__ Dv,
    float* __restrict__ out) {
  __shared__ __align__(16) char smem[147456];
  char*   H  = smem;                          // [128][1024B] swizzled
  bf16_t* Bs = (bf16_t*)(smem + 131072);      // [256][32] bf16 = 16 KB
  const int tid = threadIdx.x;
  const int c = blockIdx.x;
  const int wave = tid >> 6, lane = tid & 63;
  const int wm = wave & 1, wn = wave >> 1;
  const int lrow = lane & 15, lk = lane >> 4;
  const int ra = tid >> 2, ka = (tid & 3) * 8;

  // linear 128 KB memcpy: global image == desired swizzled LDS image
  const char* src = (const char*)Bu + (size_t)c * CHUNK * 1024;
#pragma unroll
  for (int it = 0; it < 16; ++it)
    async_load16(src + it * 8192 + tid * 16, H + it * 8192 + tid * 16);
  __syncthreads();

  // carry scan, in place: read fp16 Bu pair, write bf16 state pair to same slot
  if (tid < 256) {
    int h = tid;
    float lre = lam[h], lim = lam[DHID + h];
    float sre = Sc[c * NCH + h], sim = Sc[c * NCH + 256 + h];
    int cb = 4 * h;
#pragma unroll 4
    for (int t = 0; t < CHUNK; ++t) {
      unsigned int* p = (unsigned int*)(H + t * 1024 + (cb ^ ((t & 7) << 4)));
      unsigned int w = *p;
      float bre = f16tof(w), bim = f16tof(w >> 16);
      float nre = fmaf(lre, sre, fmaf(-lim, sim, bre));
      float nim = fmaf(lre, sim, fmaf(lim, sre, bim));
      sre = nre; sim = nim;
      *p = ((unsigned int)fTobf(sim) << 16) | (unsigned int)fTobf(sre);
    }
  }

  f32x4 acc[4][4] = {};
  for (int k0 = 0; k0 < NCH; k0 += 32) {
    __syncthreads();
    async_load16(W2 + (size_t)ra * NCH + k0 + ka, (char*)Bs + tid * 16);
    async_load16(W2 + (size_t)(128 + ra) * NCH + k0 + ka, (char*)Bs + 8192 + tid * 16);
    __syncthreads();
    bf16x8 af[4], bfr[4];
#pragma unroll
    for (int i = 0; i < 4; ++i) {
      int m = wm * 64 + i * 16 + lrow;
      af[i] = *(const bf16x8*)(H + m * 1024 + ((2 * k0 + lk * 16) ^ ((m & 7) << 4)));
    }
#pragma unroll
    for (int j = 0; j < 4; ++j)
      bfr[j] = *(const bf16x8*)(Bs + (wn * 64 + j * 16 + lrow) * 32 + lk * 8);
#pragma unroll
    for (int i = 0; i < 4; ++i)
#pragma unroll
      for (int j = 0; j < 4; ++j)
        acc[i][j] = __builtin_amdgcn_mfma_f32_16x16x32_bf16(af[i], bfr[j], acc[i][j], 0, 0, 0);
  }

#pragma unroll
  for (int i = 0; i < 4; ++i)
#pragma unroll
    for (int r = 0; r < 4; ++r) {
      int row = c * CHUNK + wm * 64 + i * 16 + lk * 4 + r;
#pragma unroll
      for (int j = 0; j < 4; ++j) {
        int col = wn * 64 + j * 16 + lrow;
        float v = acc[i][j][r] + X[(size_t)row * DMODEL + col] * Dv[col];
        out[(size_t)row * DMODEL + col] = v;
      }
    }
}

extern "C" void kernel_launch(void* const* d_in, const int* in_sizes, int n_in,
                              void* d_out, int out_size, void* d_ws, size_t ws_size,
                              hipStream_t stream) {
  const float* inputs    = (const float*)d_in[0];
  const float* nu_log    = (const float*)d_in[1];
  const float* theta_log = (const float*)d_in[2];
  const float* gamma_log = (const float*)d_in[3];
  const float* B_re      = (const float*)d_in[4];
  const float* B_im      = (const float*)d_in[5];
  const float* C_re      = (const float*)d_in[6];
  const float* C_im      = (const float*)d_in[7];
  const float* Dvec      = (const float*)d_in[8];
  float* out = (float*)d_out;

  char* w = (char*)d_ws;
  bf16_t* W1 = (bf16_t*)w; w += (size_t)NCH * DMODEL * 2;     // 256 KB
  bf16_t* W2 = (bf16_t*)w; w += (size_t)DMODEL * NCH * 2;     // 256 KB
  float* lam = (float*)w;  w += 8192;                          // 6 KB used
  bf16_t* xb = (bf16_t*)w; w += (size_t)LSEQ * DMODEL * 2;    // 16 MB
  f16_t* Bu  = (f16_t*)w;  w += (size_t)LSEQ * NCH * 2;       // 32 MB
  float* E   = (float*)w;  w += (size_t)NCHUNKS * NCH * 4;    // 512 KB
  float* Sc  = (float*)w;  w += (size_t)NCHUNKS * NCH * 4;    // 512 KB

  prep_params<<<1, 256, 0, stream>>>(nu_log, theta_log, lam);
  pack_w1<<<NCH, DMODEL, 0, stream>>>(B_re, B_im, gamma_log, W1);
  pack_w2<<<DMODEL, NCH, 0, stream>>>(C_re, C_im, W2);
  convert_x<<<(LSEQ * DMODEL) / 4 / 256, 256, 0, stream>>>(inputs, xb);

  gemm1_scan<<<dim3(2, NCHUNKS), 512, 0, stream>>>(xb, W1, Bu, lam, E);
  scan_pass2<<<DHID, NCHUNKS, 0, stream>>>(E, lam, Sc);
  scan_gemm2<<<NCHUNKS, 512, 0, stream>>>(Bu, W2, lam, Sc, inputs, Dvec, out);
}